// Round 1
// baseline (168.527 us; speedup 1.0000x reference)
//
#include <hip/hip_runtime.h>
#include <hip/hip_bf16.h>

#define N_ROWS 4096
#define DIM 512
#define TWO_N 8192

typedef __bf16 bf16x8 __attribute__((ext_vector_type(8)));
typedef float  f32x4  __attribute__((ext_vector_type(4)));

// ---------------------------------------------------------------------------
// round-to-nearest-even float -> bf16 bits
__device__ inline unsigned short f2bf(float f) {
    unsigned int u = __float_as_uint(f);
    u += 0x7fffu + ((u >> 16) & 1u);
    return (unsigned short)(u >> 16);
}

// async global -> LDS, 16 bytes per lane (wave-uniform LDS base + lane*16)
__device__ inline void g2l16(const void* g, void* l) {
    __builtin_amdgcn_global_load_lds(
        (const __attribute__((address_space(1))) void*)g,
        (__attribute__((address_space(3))) void*)l,
        16, 0, 0);
}

// ---------------------------------------------------------------------------
// Kernel 1: normalize rows of emb_i / emb_j, emit bf16 z [2N][D], pos[N],
// and zero denom[2N]. One block (256 thr) per row pair.
__global__ void normalize_kernel(const float* __restrict__ ei,
                                 const float* __restrict__ ej,
                                 unsigned short* __restrict__ zb,
                                 float* __restrict__ pos,
                                 float* __restrict__ denom) {
    int r = blockIdx.x;          // 0..4095
    int t = threadIdx.x;         // 0..255, each handles 2 dims via float2
    const float2 vi = ((const float2*)(ei + (size_t)r * DIM))[t];
    const float2 vj = ((const float2*)(ej + (size_t)r * DIM))[t];
    float si  = vi.x * vi.x + vi.y * vi.y;
    float sj  = vj.x * vj.x + vj.y * vj.y;
    float sij = vi.x * vj.x + vi.y * vj.y;

    for (int o = 32; o; o >>= 1) {
        si  += __shfl_down(si, o);
        sj  += __shfl_down(sj, o);
        sij += __shfl_down(sij, o);
    }
    __shared__ float red[3][4];
    int wave = t >> 6, lane = t & 63;
    if (lane == 0) { red[0][wave] = si; red[1][wave] = sj; red[2][wave] = sij; }
    __syncthreads();
    si  = red[0][0] + red[0][1] + red[0][2] + red[0][3];
    sj  = red[1][0] + red[1][1] + red[1][2] + red[1][3];
    sij = red[2][0] + red[2][1] + red[2][2] + red[2][3];

    float rni = 1.0f / fmaxf(sqrtf(si), 1e-12f);
    float rnj = 1.0f / fmaxf(sqrtf(sj), 1e-12f);
    if (t == 0) {
        pos[r] = sij * rni * rnj;
        denom[r] = 0.0f;
        denom[r + N_ROWS] = 0.0f;
    }
    ushort2 zi2 = make_ushort2(f2bf(vi.x * rni), f2bf(vi.y * rni));
    ushort2 zj2 = make_ushort2(f2bf(vj.x * rnj), f2bf(vj.y * rnj));
    ((ushort2*)(zb + (size_t)r * DIM))[t] = zi2;
    ((ushort2*)(zb + (size_t)(r + N_ROWS) * DIM))[t] = zj2;
}

// ---------------------------------------------------------------------------
// Kernel 2: 128x128-tile bf16 MFMA GEMM of z·zT, fused exp(2*sim) with
// diagonal masked, row-summed into denom[] via LDS combine + global atomics.
// Block = 256 threads = 4 waves (2x2 of 64x64 wave tiles). BK = 32.
__global__ __launch_bounds__(256) void gemm_exp_kernel(
        const unsigned short* __restrict__ zb,
        float* __restrict__ denom) {
    const int rb = blockIdx.y * 128;   // row tile base (global z row)
    const int cb = blockIdx.x * 128;   // col tile base

    const int tid  = threadIdx.x;
    const int wave = tid >> 6;
    const int lane = tid & 63;
    const int quad = lane >> 4;        // 0..3
    const int m    = lane & 15;        // 0..15
    const int wm   = (wave >> 1) * 64; // wave row offset in tile
    const int wn   = (wave & 1) * 64;  // wave col offset in tile

    __shared__ __align__(16) unsigned short As[128 * 32];
    __shared__ __align__(16) unsigned short Bs[128 * 32];

    f32x4 acc[4][4];
    #pragma unroll
    for (int i = 0; i < 4; ++i)
        #pragma unroll
        for (int j = 0; j < 4; ++j)
            #pragma unroll
            for (int r = 0; r < 4; ++r) acc[i][j][r] = 0.0f;

    // staging geometry: chunk = 1024B = 16 rows x 64B; wave w stages chunks
    // 2w, 2w+1 of both A and B. lane covers (row = l>>2, 16B quad = l&3).
    const int srow = lane >> 2;
    const int sk   = (lane & 3) * 8;   // bf16 elements

    for (int k0 = 0; k0 < DIM; k0 += 32) {
        __syncthreads();   // previous iter's ds_reads done before overwrite
        #pragma unroll
        for (int cc = 0; cc < 2; ++cc) {
            int c   = 2 * wave + cc;
            int row = c * 16 + srow;
            const unsigned short* ga = zb + (size_t)(rb + row) * DIM + k0 + sk;
            const unsigned short* gb = zb + (size_t)(cb + row) * DIM + k0 + sk;
            g2l16(ga, As + c * 512);
            g2l16(gb, Bs + c * 512);
        }
        __syncthreads();   // drains vmcnt (global_load_lds) per barrier semantics

        bf16x8 af[4], bfr[4];
        #pragma unroll
        for (int i = 0; i < 4; ++i)
            af[i] = *(const bf16x8*)(As + (wm + i * 16 + m) * 32 + quad * 8);
        #pragma unroll
        for (int j = 0; j < 4; ++j)
            bfr[j] = *(const bf16x8*)(Bs + (wn + j * 16 + m) * 32 + quad * 8);

        #pragma unroll
        for (int i = 0; i < 4; ++i)
            #pragma unroll
            for (int j = 0; j < 4; ++j)
                acc[i][j] = __builtin_amdgcn_mfma_f32_16x16x32_bf16(
                    af[i], bfr[j], acc[i][j], 0, 0, 0);
    }

    // ---- epilogue: exp(2*sim), mask diagonal, reduce rows ----
    __syncthreads();
    float* rs = (float*)As;            // reuse LDS: rowsum[128]
    if (tid < 128) rs[tid] = 0.0f;
    __syncthreads();

    #pragma unroll
    for (int i = 0; i < 4; ++i) {
        #pragma unroll
        for (int r = 0; r < 4; ++r) {
            int lrow = wm + i * 16 + quad * 4 + r;    // local row 0..127
            int grow = rb + lrow;
            float s = 0.0f;
            #pragma unroll
            for (int j = 0; j < 4; ++j) {
                int gcol = cb + wn + j * 16 + m;
                float v  = acc[i][j][r];
                s += (grow == gcol) ? 0.0f : __expf(2.0f * v);
            }
            // sum across the 16 lanes of this quad-row group (bits 0..3)
            s += __shfl_xor(s, 1);
            s += __shfl_xor(s, 2);
            s += __shfl_xor(s, 4);
            s += __shfl_xor(s, 8);
            if (m == 0) atomicAdd(&rs[lrow], s);
        }
    }
    __syncthreads();
    if (tid < 128) atomicAdd(&denom[rb + tid], rs[tid]);
}

// ---------------------------------------------------------------------------
// Kernel 3: final loss = mean_r [ log(denom[r]) - 2*pos[r % N] ]
__global__ void loss_kernel(const float* __restrict__ pos,
                            const float* __restrict__ denom,
                            float* __restrict__ out) {
    int t = threadIdx.x;   // 256 threads, 1 block
    float s = 0.0f;
    for (int r = t; r < TWO_N; r += 256)
        s += logf(denom[r]) - 2.0f * pos[r & (N_ROWS - 1)];
    for (int o = 32; o; o >>= 1) s += __shfl_down(s, o);
    __shared__ float red[4];
    if ((t & 63) == 0) red[t >> 6] = s;
    __syncthreads();
    if (t == 0) out[0] = (red[0] + red[1] + red[2] + red[3]) / (float)TWO_N;
}

// ---------------------------------------------------------------------------
extern "C" void kernel_launch(void* const* d_in, const int* in_sizes, int n_in,
                              void* d_out, int out_size, void* d_ws, size_t ws_size,
                              hipStream_t stream) {
    const float* ei = (const float*)d_in[0];
    const float* ej = (const float*)d_in[1];

    // ws layout: zb (bf16, 2N*D = 8 MB) | pos (N f32) | denom (2N f32)
    unsigned short* zb  = (unsigned short*)d_ws;
    float* pos   = (float*)((char*)d_ws + (size_t)TWO_N * DIM * sizeof(unsigned short));
    float* denom = pos + N_ROWS;
    float* out   = (float*)d_out;

    normalize_kernel<<<N_ROWS, 256, 0, stream>>>(ei, ej, zb, pos, denom);
    dim3 grid(TWO_N / 128, TWO_N / 128);
    gemm_exp_kernel<<<grid, 256, 0, stream>>>(zb, denom);
    loss_kernel<<<1, 256, 0, stream>>>(pos, denom, out);
}

// Round 2
// 147.125 us; speedup vs baseline: 1.1455x; 1.1455x over previous
//
#include <hip/hip_runtime.h>
#include <hip/hip_bf16.h>

#define N_ROWS 4096
#define DIM 512
#define TWO_N 8192

typedef __bf16 bf16x8 __attribute__((ext_vector_type(8)));
typedef float  f32x4  __attribute__((ext_vector_type(4)));

// ---------------------------------------------------------------------------
// round-to-nearest-even float -> bf16 bits
__device__ inline unsigned short f2bf(float f) {
    unsigned int u = __float_as_uint(f);
    u += 0x7fffu + ((u >> 16) & 1u);
    return (unsigned short)(u >> 16);
}

// async global -> LDS, 16 bytes per lane (wave-uniform LDS base + lane*16)
__device__ inline void g2l16(const void* g, void* l) {
    __builtin_amdgcn_global_load_lds(
        (const __attribute__((address_space(1))) void*)g,
        (__attribute__((address_space(3))) void*)l,
        16, 0, 0);
}

// ---------------------------------------------------------------------------
// Kernel 1: normalize rows of emb_i / emb_j, emit bf16 z [2N][D], pos[N],
// and zero denom[2N]. One block (256 thr) per row pair.
__global__ void normalize_kernel(const float* __restrict__ ei,
                                 const float* __restrict__ ej,
                                 unsigned short* __restrict__ zb,
                                 float* __restrict__ pos,
                                 float* __restrict__ denom) {
    int r = blockIdx.x;          // 0..4095
    int t = threadIdx.x;         // 0..255, each handles 2 dims via float2
    const float2 vi = ((const float2*)(ei + (size_t)r * DIM))[t];
    const float2 vj = ((const float2*)(ej + (size_t)r * DIM))[t];
    float si  = vi.x * vi.x + vi.y * vi.y;
    float sj  = vj.x * vj.x + vj.y * vj.y;
    float sij = vi.x * vj.x + vi.y * vj.y;

    for (int o = 32; o; o >>= 1) {
        si  += __shfl_down(si, o);
        sj  += __shfl_down(sj, o);
        sij += __shfl_down(sij, o);
    }
    __shared__ float red[3][4];
    int wave = t >> 6, lane = t & 63;
    if (lane == 0) { red[0][wave] = si; red[1][wave] = sj; red[2][wave] = sij; }
    __syncthreads();
    si  = red[0][0] + red[0][1] + red[0][2] + red[0][3];
    sj  = red[1][0] + red[1][1] + red[1][2] + red[1][3];
    sij = red[2][0] + red[2][1] + red[2][2] + red[2][3];

    float rni = 1.0f / fmaxf(sqrtf(si), 1e-12f);
    float rnj = 1.0f / fmaxf(sqrtf(sj), 1e-12f);
    if (t == 0) {
        pos[r] = sij * rni * rnj;
        denom[r] = 0.0f;
        denom[r + N_ROWS] = 0.0f;
    }
    ushort2 zi2 = make_ushort2(f2bf(vi.x * rni), f2bf(vi.y * rni));
    ushort2 zj2 = make_ushort2(f2bf(vj.x * rnj), f2bf(vj.y * rnj));
    ((ushort2*)(zb + (size_t)r * DIM))[t] = zi2;
    ((ushort2*)(zb + (size_t)(r + N_ROWS) * DIM))[t] = zj2;
}

// ---------------------------------------------------------------------------
// Kernel 2: upper-triangular 128x128-tile bf16 MFMA GEMM of z·zT.
// sim is symmetric: block (by<=bx) contributes exp row-sums to denom[rb..]
// and (off-diag) column-sums to denom[cb..]. Diag blocks mask grow==gcol.
// LDS granule XOR swizzle (row*4 + (q^(row&3))) makes ds_read_b128
// conflict-free while keeping global_load_lds's lane*16 contiguity.
__global__ __launch_bounds__(256) void gemm_exp_kernel(
        const unsigned short* __restrict__ zb,
        float* __restrict__ denom) {
    const int bx = blockIdx.x, by = blockIdx.y;
    if (by > bx) return;                 // lower triangle: covered by symmetry
    const int rb = by * 128;             // row tile base
    const int cb = bx * 128;             // col tile base
    const bool diag = (rb == cb);

    const int tid  = threadIdx.x;
    const int wave = tid >> 6;
    const int lane = tid & 63;
    const int quad = lane >> 4;          // 0..3
    const int m    = lane & 15;          // 0..15
    const int wm   = (wave >> 1) * 64;   // wave row offset in tile
    const int wn   = (wave & 1) * 64;    // wave col offset in tile
    const int sq   = quad ^ (m & 3);     // swizzled 16B-granule index for reads

    __shared__ __align__(16) unsigned short As[128 * 32];
    __shared__ __align__(16) unsigned short Bs[128 * 32];

    f32x4 acc[4][4];
    #pragma unroll
    for (int i = 0; i < 4; ++i)
        #pragma unroll
        for (int j = 0; j < 4; ++j)
            #pragma unroll
            for (int r = 0; r < 4; ++r) acc[i][j][r] = 0.0f;

    // staging: chunk = 1024B = 16 rows x 4 granules; wave w stages chunks
    // 2w,2w+1. LDS slot lane*16 holds granule (row=lane>>2, q=(lane&3)^(row&3)).
    const int srow = lane >> 2;
    const int sk   = (((lane & 3) ^ (srow & 3)) * 8);  // swizzled global granule

    for (int k0 = 0; k0 < DIM; k0 += 32) {
        __syncthreads();   // previous iter's ds_reads done before overwrite
        #pragma unroll
        for (int cc = 0; cc < 2; ++cc) {
            int c   = 2 * wave + cc;
            int row = c * 16 + srow;
            const unsigned short* ga = zb + (size_t)(rb + row) * DIM + k0 + sk;
            const unsigned short* gb = zb + (size_t)(cb + row) * DIM + k0 + sk;
            g2l16(ga, As + c * 512);
            g2l16(gb, Bs + c * 512);
        }
        __syncthreads();   // drains vmcnt (global_load_lds) per barrier semantics

        bf16x8 af[4], bfr[4];
        #pragma unroll
        for (int i = 0; i < 4; ++i)
            af[i] = *(const bf16x8*)(As + (wm + i * 16 + m) * 32 + sq * 8);
        #pragma unroll
        for (int j = 0; j < 4; ++j)
            bfr[j] = *(const bf16x8*)(Bs + (wn + j * 16 + m) * 32 + sq * 8);

        #pragma unroll
        for (int i = 0; i < 4; ++i)
            #pragma unroll
            for (int j = 0; j < 4; ++j)
                acc[i][j] = __builtin_amdgcn_mfma_f32_16x16x32_bf16(
                    af[i], bfr[j], acc[i][j], 0, 0, 0);
    }

    // ---- epilogue: exp(2*sim), mask diag, row sums (+ col sums off-diag) ----
    __syncthreads();
    float* rs = (float*)As;            // reuse LDS: rowsum[128] | colsum[128]
    float* cs = rs + 128;
    if (tid < 128) { rs[tid] = 0.0f; cs[tid] = 0.0f; }
    __syncthreads();

    float colsum[4] = {0.0f, 0.0f, 0.0f, 0.0f};
    #pragma unroll
    for (int i = 0; i < 4; ++i) {
        #pragma unroll
        for (int r = 0; r < 4; ++r) {
            int lrow = wm + i * 16 + quad * 4 + r;    // local row 0..127
            int grow = rb + lrow;
            float s = 0.0f;
            #pragma unroll
            for (int j = 0; j < 4; ++j) {
                int gcol = cb + wn + j * 16 + m;
                float v  = __expf(2.0f * acc[i][j][r]);
                v = (grow == gcol) ? 0.0f : v;
                s += v;
                colsum[j] += v;
            }
            // sum across the 16 lanes of this quad-row group (bits 0..3)
            s += __shfl_xor(s, 1);
            s += __shfl_xor(s, 2);
            s += __shfl_xor(s, 4);
            s += __shfl_xor(s, 8);
            if (m == 0) atomicAdd(&rs[lrow], s);
        }
    }
    if (!diag) {
        #pragma unroll
        for (int j = 0; j < 4; ++j) {
            float s = colsum[j];       // this wave's 64 rows, col wn+j*16+m
            s += __shfl_xor(s, 16);    // combine across quads (rows)
            s += __shfl_xor(s, 32);
            if (quad == 0) atomicAdd(&cs[wn + j * 16 + m], s);
        }
    }
    __syncthreads();
    if (tid < 128) {
        atomicAdd(&denom[rb + tid], rs[tid]);
        if (!diag) atomicAdd(&denom[cb + tid], cs[tid]);
    }
}

// ---------------------------------------------------------------------------
// Kernel 3: final loss = mean_r [ log(denom[r]) - 2*pos[r % N] ]
__global__ void loss_kernel(const float* __restrict__ pos,
                            const float* __restrict__ denom,
                            float* __restrict__ out) {
    int t = threadIdx.x;   // 256 threads, 1 block
    float s = 0.0f;
    for (int r = t; r < TWO_N; r += 256)
        s += logf(denom[r]) - 2.0f * pos[r & (N_ROWS - 1)];
    for (int o = 32; o; o >>= 1) s += __shfl_down(s, o);
    __shared__ float red[4];
    if ((t & 63) == 0) red[t >> 6] = s;
    __syncthreads();
    if (t == 0) out[0] = (red[0] + red[1] + red[2] + red[3]) / (float)TWO_N;
}

// ---------------------------------------------------------------------------
extern "C" void kernel_launch(void* const* d_in, const int* in_sizes, int n_in,
                              void* d_out, int out_size, void* d_ws, size_t ws_size,
                              hipStream_t stream) {
    const float* ei = (const float*)d_in[0];
    const float* ej = (const float*)d_in[1];

    // ws layout: zb (bf16, 2N*D = 8 MB) | pos (N f32) | denom (2N f32)
    unsigned short* zb  = (unsigned short*)d_ws;
    float* pos   = (float*)((char*)d_ws + (size_t)TWO_N * DIM * sizeof(unsigned short));
    float* denom = pos + N_ROWS;
    float* out   = (float*)d_out;

    normalize_kernel<<<N_ROWS, 256, 0, stream>>>(ei, ej, zb, pos, denom);
    dim3 grid(TWO_N / 128, TWO_N / 128);
    gemm_exp_kernel<<<grid, 256, 0, stream>>>(zb, denom);
    loss_kernel<<<1, 256, 0, stream>>>(pos, denom, out);
}

// Round 3
// 123.231 us; speedup vs baseline: 1.3676x; 1.1939x over previous
//
#include <hip/hip_runtime.h>
#include <hip/hip_bf16.h>

#define N_ROWS 4096
#define DIM 512
#define TWO_N 8192
#define NTILE 64                 // 8192 / 128
#define NTRI  (NTILE * (NTILE + 1) / 2)   // 2080 upper-tri blocks

typedef __bf16 bf16x8 __attribute__((ext_vector_type(8)));
typedef float  f32x4  __attribute__((ext_vector_type(4)));

// ---------------------------------------------------------------------------
// round-to-nearest-even float -> bf16 bits
__device__ inline unsigned short f2bf(float f) {
    unsigned int u = __float_as_uint(f);
    u += 0x7fffu + ((u >> 16) & 1u);
    return (unsigned short)(u >> 16);
}

// async global -> LDS, 16 bytes per lane (wave-uniform LDS base + lane*16)
__device__ inline void g2l16(const void* g, void* l) {
    __builtin_amdgcn_global_load_lds(
        (const __attribute__((address_space(1))) void*)g,
        (__attribute__((address_space(3))) void*)l,
        16, 0, 0);
}

// ---------------------------------------------------------------------------
// Kernel 1: normalize rows of emb_i / emb_j, emit bf16 z [2N][D], pos[N],
// zero denom[2N] and out[0]. One block (256 thr) per row pair.
__global__ void normalize_kernel(const float* __restrict__ ei,
                                 const float* __restrict__ ej,
                                 unsigned short* __restrict__ zb,
                                 float* __restrict__ pos,
                                 float* __restrict__ denom,
                                 float* __restrict__ out) {
    int r = blockIdx.x;          // 0..4095
    int t = threadIdx.x;         // 0..255, each handles 2 dims via float2
    const float2 vi = ((const float2*)(ei + (size_t)r * DIM))[t];
    const float2 vj = ((const float2*)(ej + (size_t)r * DIM))[t];
    float si  = vi.x * vi.x + vi.y * vi.y;
    float sj  = vj.x * vj.x + vj.y * vj.y;
    float sij = vi.x * vj.x + vi.y * vj.y;

    for (int o = 32; o; o >>= 1) {
        si  += __shfl_down(si, o);
        sj  += __shfl_down(sj, o);
        sij += __shfl_down(sij, o);
    }
    __shared__ float red[3][4];
    int wave = t >> 6, lane = t & 63;
    if (lane == 0) { red[0][wave] = si; red[1][wave] = sj; red[2][wave] = sij; }
    __syncthreads();
    si  = red[0][0] + red[0][1] + red[0][2] + red[0][3];
    sj  = red[1][0] + red[1][1] + red[1][2] + red[1][3];
    sij = red[2][0] + red[2][1] + red[2][2] + red[2][3];

    float rni = 1.0f / fmaxf(sqrtf(si), 1e-12f);
    float rnj = 1.0f / fmaxf(sqrtf(sj), 1e-12f);
    if (t == 0) {
        pos[r] = sij * rni * rnj;
        denom[r] = 0.0f;
        denom[r + N_ROWS] = 0.0f;
        if (r == 0) out[0] = 0.0f;   // accumulated by loss_kernel (stream-ordered)
    }
    ushort2 zi2 = make_ushort2(f2bf(vi.x * rni), f2bf(vi.y * rni));
    ushort2 zj2 = make_ushort2(f2bf(vj.x * rnj), f2bf(vj.y * rnj));
    ((ushort2*)(zb + (size_t)r * DIM))[t] = zi2;
    ((ushort2*)(zb + (size_t)(r + N_ROWS) * DIM))[t] = zj2;
}

// ---------------------------------------------------------------------------
// Kernel 2: upper-triangular 128x128-tile bf16 MFMA GEMM of z·zT (linear
// triangular grid, no empty blocks). Block (by<=bx) adds exp row-sums to
// denom[rb..] and (off-diag) col-sums to denom[cb..]; diag masks grow==gcol.
// LDS granule swizzle q_phys = q ^ ((row>>1)&3): fragment-read bank starts
// cover all 8 granule offsets exactly 2x per 16-lane phase -> 2-way (free).
__global__ __launch_bounds__(256) void gemm_exp_kernel(
        const unsigned short* __restrict__ zb,
        float* __restrict__ denom) {
    // ---- linear index -> (by, bx), by <= bx, row-major over by ----
    const int t = blockIdx.x;
    int by = (int)(0.5f * (2.0f * NTILE + 1.0f -
              sqrtf((2.0f * NTILE + 1.0f) * (2.0f * NTILE + 1.0f) - 8.0f * t)));
    while ((by + 1) * NTILE - ((by + 1) * by) / 2 <= t) ++by;
    while (by * NTILE - (by * (by - 1)) / 2 > t) --by;
    const int bx = by + (t - (by * NTILE - (by * (by - 1)) / 2));

    const int rb = by * 128;             // row tile base
    const int cb = bx * 128;             // col tile base
    const bool diag = (rb == cb);

    const int tid  = threadIdx.x;
    const int wave = tid >> 6;
    const int lane = tid & 63;
    const int quad = lane >> 4;          // 0..3
    const int m    = lane & 15;          // 0..15
    const int wm   = (wave >> 1) * 64;   // wave row offset in tile
    const int wn   = (wave & 1) * 64;    // wave col offset in tile
    const int sq   = quad ^ ((m >> 1) & 3);  // swizzled granule for reads

    __shared__ __align__(16) unsigned short As[128 * 32];
    __shared__ __align__(16) unsigned short Bs[128 * 32];

    f32x4 acc[4][4];
    #pragma unroll
    for (int i = 0; i < 4; ++i)
        #pragma unroll
        for (int j = 0; j < 4; ++j)
            #pragma unroll
            for (int r = 0; r < 4; ++r) acc[i][j][r] = 0.0f;

    // staging: chunk = 1024B = 16 rows x 4 granules; wave w stages chunks
    // 2w,2w+1. Phys slot lane*16 = (row=lane>>2, pq=lane&3) holds global
    // granule pq ^ ((row>>1)&3)  [(row>>1)&3 == ((lane>>3)&3) within chunk].
    const int srow = lane >> 2;
    const int sk   = (((lane & 3) ^ ((lane >> 3) & 3)) * 8);

    for (int k0 = 0; k0 < DIM; k0 += 32) {
        __syncthreads();   // previous iter's ds_reads done before overwrite
        #pragma unroll
        for (int cc = 0; cc < 2; ++cc) {
            int c   = 2 * wave + cc;
            int row = c * 16 + srow;
            const unsigned short* ga = zb + (size_t)(rb + row) * DIM + k0 + sk;
            const unsigned short* gb = zb + (size_t)(cb + row) * DIM + k0 + sk;
            g2l16(ga, As + c * 512);
            g2l16(gb, Bs + c * 512);
        }
        __syncthreads();   // drains vmcnt (global_load_lds) per barrier semantics

        bf16x8 af[4], bfr[4];
        #pragma unroll
        for (int i = 0; i < 4; ++i)
            af[i] = *(const bf16x8*)(As + (wm + i * 16 + m) * 32 + sq * 8);
        #pragma unroll
        for (int j = 0; j < 4; ++j)
            bfr[j] = *(const bf16x8*)(Bs + (wn + j * 16 + m) * 32 + sq * 8);

        #pragma unroll
        for (int i = 0; i < 4; ++i)
            #pragma unroll
            for (int j = 0; j < 4; ++j)
                acc[i][j] = __builtin_amdgcn_mfma_f32_16x16x32_bf16(
                    af[i], bfr[j], acc[i][j], 0, 0, 0);
    }

    // ---- epilogue: exp(2*sim), mask diag, row sums (+ col sums off-diag) ----
    __syncthreads();
    float* rs = (float*)As;            // reuse LDS: rowsum[128] | colsum[128]
    float* cs = rs + 128;
    if (tid < 128) { rs[tid] = 0.0f; cs[tid] = 0.0f; }
    __syncthreads();

    float colsum[4] = {0.0f, 0.0f, 0.0f, 0.0f};
    #pragma unroll
    for (int i = 0; i < 4; ++i) {
        #pragma unroll
        for (int r = 0; r < 4; ++r) {
            int lrow = wm + i * 16 + quad * 4 + r;    // local row 0..127
            int grow = rb + lrow;
            float s = 0.0f;
            #pragma unroll
            for (int j = 0; j < 4; ++j) {
                int gcol = cb + wn + j * 16 + m;
                float v  = __expf(2.0f * acc[i][j][r]);
                v = (grow == gcol) ? 0.0f : v;
                s += v;
                colsum[j] += v;
            }
            // sum across the 16 lanes of this quad-row group (bits 0..3)
            s += __shfl_xor(s, 1);
            s += __shfl_xor(s, 2);
            s += __shfl_xor(s, 4);
            s += __shfl_xor(s, 8);
            if (m == 0) atomicAdd(&rs[lrow], s);
        }
    }
    if (!diag) {
        #pragma unroll
        for (int j = 0; j < 4; ++j) {
            float s = colsum[j];       // this wave's 64 rows, col wn+j*16+m
            s += __shfl_xor(s, 16);    // combine across quads (rows)
            s += __shfl_xor(s, 32);
            if (quad == 0) atomicAdd(&cs[wn + j * 16 + m], s);
        }
    }
    __syncthreads();
    if (tid < 128) {
        atomicAdd(&denom[rb + tid], rs[tid]);
        if (!diag) atomicAdd(&denom[cb + tid], cs[tid]);
    }
}

// ---------------------------------------------------------------------------
// Kernel 3: loss += sum_r [ log(denom[r]) - 2*pos[r % N] ] / 2N.
// 32 blocks x 256 threads, one row each; per-block reduce + one atomic.
__global__ void loss_kernel(const float* __restrict__ pos,
                            const float* __restrict__ denom,
                            float* __restrict__ out) {
    int r = blockIdx.x * 256 + threadIdx.x;   // 0..8191
    float s = __logf(denom[r]) - 2.0f * pos[r & (N_ROWS - 1)];
    for (int o = 32; o; o >>= 1) s += __shfl_down(s, o);
    __shared__ float red[4];
    int t = threadIdx.x;
    if ((t & 63) == 0) red[t >> 6] = s;
    __syncthreads();
    if (t == 0)
        atomicAdd(out, (red[0] + red[1] + red[2] + red[3]) / (float)TWO_N);
}

// ---------------------------------------------------------------------------
extern "C" void kernel_launch(void* const* d_in, const int* in_sizes, int n_in,
                              void* d_out, int out_size, void* d_ws, size_t ws_size,
                              hipStream_t stream) {
    const float* ei = (const float*)d_in[0];
    const float* ej = (const float*)d_in[1];

    // ws layout: zb (bf16, 2N*D = 8 MB) | pos (N f32) | denom (2N f32)
    unsigned short* zb  = (unsigned short*)d_ws;
    float* pos   = (float*)((char*)d_ws + (size_t)TWO_N * DIM * sizeof(unsigned short));
    float* denom = pos + N_ROWS;
    float* out   = (float*)d_out;

    normalize_kernel<<<N_ROWS, 256, 0, stream>>>(ei, ej, zb, pos, denom, out);
    gemm_exp_kernel<<<NTRI, 256, 0, stream>>>(zb, denom);
    loss_kernel<<<TWO_N / 256, 256, 0, stream>>>(pos, denom, out);
}